// Round 1
// baseline (119.023 us; speedup 1.0000x reference)
//
#include <hip/hip_runtime.h>

#define BB 4
#define NN 8192
#define MM 8192
#define CHUNKS 16      // M split into 16 chunks of 512 targets
#define CHUNK 512      // targets per chunk (== LDS tile, 8 KB as float4)
#define VSRC 4         // source points per thread
#define TPB 256

// ws layout:
//   src4 : [BB*NN] float4   (x,y,z,|p|^2)
//   tgt4 : [BB*MM] float4
//   minb : [2][BB*NN] uint  (float bits, atomicMin'd; d2>=0 so uint order == float order)

__global__ void prep_kernel(const float* __restrict__ s, const float* __restrict__ t,
                            float4* __restrict__ s4, float4* __restrict__ t4) {
    int i = blockIdx.x * blockDim.x + threadIdx.x;
    if (i < BB * NN) {
        float a = s[3*i], b = s[3*i+1], c = s[3*i+2];
        s4[i] = make_float4(a, b, c, a*a + b*b + c*c);
        float d = t[3*i], e = t[3*i+1], f = t[3*i+2];
        t4[i] = make_float4(d, e, f, d*d + e*e + f*f);
    }
}

__global__ __launch_bounds__(TPB) void minpass_kernel(const float4* __restrict__ s4,
                                                      const float4* __restrict__ t4,
                                                      unsigned int* __restrict__ minb) {
    __shared__ float4 tile[CHUNK];

    int bid = blockIdx.x;
    int dir = bid >> 9;          // 512 blocks per direction
    bid &= 511;
    const int NT = NN / (TPB * VSRC);      // 8 src tiles per batch
    int c  = bid % CHUNKS;
    int tt = (bid / CHUNKS) % NT;
    int b  = bid / (CHUNKS * NT);

    const float4* __restrict__ S = dir ? t4 : s4;
    const float4* __restrict__ T = dir ? s4 : t4;
    unsigned int* __restrict__ out = minb + dir * (BB * NN);

    int tid = threadIdx.x;
    int nbase = tt * (TPB * VSRC);

    // load this thread's 4 source points (coalesced: stride TPB)
    float4 sp[VSRC];
#pragma unroll
    for (int v = 0; v < VSRC; ++v)
        sp[v] = S[b * NN + nbase + v * TPB + tid];

    // stage target chunk into LDS (coalesced float4)
#pragma unroll
    for (int k = tid; k < CHUNK; k += TPB)
        tile[k] = T[b * MM + c * CHUNK + k];
    __syncthreads();

    float acc[VSRC];
#pragma unroll
    for (int v = 0; v < VSRC; ++v) acc[v] = 3.0e38f;

#pragma unroll 2
    for (int j = 0; j < CHUNK; j += 2) {
        float4 y0 = tile[j];
        float4 y1 = tile[j + 1];
#pragma unroll
        for (int v = 0; v < VSRC; ++v) {
            // p = <x, y>  (contracts to mul + 2 fma)
            float p0 = sp[v].x * y0.x + sp[v].y * y0.y + sp[v].z * y0.z;
            float p1 = sp[v].x * y1.x + sp[v].y * y1.y + sp[v].z * y1.z;
            // h = |y|^2 - 2p  (fma(-2, p, y.w))
            float h0 = __builtin_fmaf(-2.0f, p0, y0.w);
            float h1 = __builtin_fmaf(-2.0f, p1, y1.w);
            acc[v] = fminf(acc[v], fminf(h0, h1));   // -> v_min3_f32
        }
    }

#pragma unroll
    for (int v = 0; v < VSRC; ++v) {
        float val = sp[v].w + acc[v];          // d2_min over this chunk, >= 0
        atomicMin(&out[b * NN + nbase + v * TPB + tid], __float_as_uint(val));
    }
}

__global__ void finalize_kernel(const unsigned int* __restrict__ minb, float* __restrict__ out) {
    float s0 = 0.f, s1 = 0.f;
    for (int i = threadIdx.x; i < BB * NN; i += TPB) {
        s0 += __uint_as_float(minb[i]);
        s1 += __uint_as_float(minb[BB * NN + i]);
    }
#pragma unroll
    for (int o = 32; o; o >>= 1) {
        s0 += __shfl_down(s0, o);
        s1 += __shfl_down(s1, o);
    }
    __shared__ float w0[TPB / 64], w1[TPB / 64];
    int wave = threadIdx.x >> 6;
    if ((threadIdx.x & 63) == 0) { w0[wave] = s0; w1[wave] = s1; }
    __syncthreads();
    if (threadIdx.x == 0) {
        float a = 0.f, bsum = 0.f;
#pragma unroll
        for (int w = 0; w < TPB / 64; ++w) { a += w0[w]; bsum += w1[w]; }
        out[0] = 0.01f * (a / (float)(BB * NN) + bsum / (float)(BB * MM));
    }
}

extern "C" void kernel_launch(void* const* d_in, const int* in_sizes, int n_in,
                              void* d_out, int out_size, void* d_ws, size_t ws_size,
                              hipStream_t stream) {
    const float* s = (const float*)d_in[0];
    const float* t = (const float*)d_in[1];

    float4* s4 = (float4*)d_ws;
    float4* t4 = s4 + BB * NN;
    unsigned int* minb = (unsigned int*)(t4 + BB * MM);

    hipMemsetAsync(minb, 0x7f, 2 * BB * NN * sizeof(unsigned int), stream);
    prep_kernel<<<(BB * NN + 255) / 256, 256, 0, stream>>>(s, t, s4, t4);
    minpass_kernel<<<2 * BB * (NN / (TPB * VSRC)) * CHUNKS, TPB, 0, stream>>>(s4, t4, minb);
    finalize_kernel<<<1, TPB, 0, stream>>>(minb, (float*)d_out);
}

// Round 2
// 57.070 us; speedup vs baseline: 2.0856x; 2.0856x over previous
//
#include <hip/hip_runtime.h>

#define BB 4
#define NN 8192
#define MM 8192
#define TPB 256
#define VSRC 4
#define CS 16              // M split into 16 chunks, one block each (atomicMin combine)
#define CHUNK 512          // targets per chunk
#define PAIRS (CHUNK / 2)  // 256 target-pairs staged in LDS (8 KB)
#define INF_BITS 0x7f7f7f7fu

typedef float f2 __attribute__((ext_vector_type(2)));

// ws layout (float4 units):
//   s4 [32768]  : source points as {x,y,z,|p|^2}
//   t4 [32768]  : target points likewise
//   sA [16384]  : source pair-transposed {x0,x1,y0,y1}
//   sB [16384]  : source pair-transposed {z0,z1,w0,w1}
//   tA [16384], tB [16384] : same for target
//   minb [65536 u32] : per-point running min bits (dir0 then dir1)

__global__ __launch_bounds__(256) void prep_kernel(
        const float* __restrict__ s, const float* __restrict__ t,
        float4* __restrict__ s4, float4* __restrict__ t4,
        float4* __restrict__ sA, float4* __restrict__ sB,
        float4* __restrict__ tA, float4* __restrict__ tB,
        uint4* __restrict__ minb4) {
    int i = blockIdx.x * blockDim.x + threadIdx.x;   // pair index, 16384 total
    if (i >= BB * NN / 2) return;
    {
        float a0 = s[6*i+0], b0 = s[6*i+1], c0 = s[6*i+2];
        float a1 = s[6*i+3], b1 = s[6*i+4], c1 = s[6*i+5];
        float w0 = a0*a0 + b0*b0 + c0*c0;
        float w1 = a1*a1 + b1*b1 + c1*c1;
        s4[2*i+0] = make_float4(a0, b0, c0, w0);
        s4[2*i+1] = make_float4(a1, b1, c1, w1);
        sA[i] = make_float4(a0, a1, b0, b1);
        sB[i] = make_float4(c0, c1, w0, w1);
    }
    {
        float a0 = t[6*i+0], b0 = t[6*i+1], c0 = t[6*i+2];
        float a1 = t[6*i+3], b1 = t[6*i+4], c1 = t[6*i+5];
        float w0 = a0*a0 + b0*b0 + c0*c0;
        float w1 = a1*a1 + b1*b1 + c1*c1;
        t4[2*i+0] = make_float4(a0, b0, c0, w0);
        t4[2*i+1] = make_float4(a1, b1, c1, w1);
        tA[i] = make_float4(a0, a1, b0, b1);
        tB[i] = make_float4(c0, c1, w0, w1);
    }
    minb4[i] = make_uint4(INF_BITS, INF_BITS, INF_BITS, INF_BITS);  // 16384*4 = 65536
}

__global__ __launch_bounds__(TPB) void minpass_kernel(
        const float4* __restrict__ s4, const float4* __restrict__ t4,
        const float4* __restrict__ sA, const float4* __restrict__ sB,
        const float4* __restrict__ tA, const float4* __restrict__ tB,
        unsigned int* __restrict__ minb) {
    __shared__ float4 TA[PAIRS];
    __shared__ float4 TB[PAIRS];

    int bid = blockIdx.x;
    int dir = bid >> 9;           // 512 blocks per direction
    bid &= 511;
    int c  = bid & (CS - 1);      // chunk of M
    int tt = (bid >> 4) & 7;      // src tile (NT = NN/(TPB*VSRC) = 8)
    int b  = bid >> 7;            // batch

    const float4* __restrict__ S  = dir ? t4 : s4;   // source point layout
    const float4* __restrict__ PA = dir ? sA : tA;   // target pair layout
    const float4* __restrict__ PB = dir ? sB : tB;
    unsigned int* __restrict__ out = minb + dir * (BB * NN);

    int tid = threadIdx.x;

    // stage target chunk (pair-transposed) into LDS: 1 float4 each array per thread
    TA[tid] = PA[b * (MM / 2) + c * PAIRS + tid];
    TB[tid] = PB[b * (MM / 2) + c * PAIRS + tid];

    // load this thread's source points; fold the -2 into the coords
    int nbase = tt * (TPB * VSRC);
    f2 xn[VSRC], yn[VSRC], zn[VSRC];
    float sw[VSRC], acc[VSRC];
#pragma unroll
    for (int v = 0; v < VSRC; ++v) {
        float4 sp = S[b * NN + nbase + v * TPB + tid];
        float x = -2.0f * sp.x, y = -2.0f * sp.y, z = -2.0f * sp.z;
        xn[v] = (f2){x, x};
        yn[v] = (f2){y, y};
        zn[v] = (f2){z, z};
        sw[v] = sp.w;
        acc[v] = 3.0e38f;
    }
    __syncthreads();

#pragma unroll 2
    for (int j = 0; j < PAIRS; ++j) {
        float4 A = TA[j];                 // {x0,x1,y0,y1} broadcast (no conflict)
        float4 B = TB[j];                 // {z0,z1,w0,w1}
        f2 x01 = (f2){A.x, A.y};
        f2 y01 = (f2){A.z, A.w};
        f2 z01 = (f2){B.x, B.y};
        f2 w01 = (f2){B.z, B.w};
#pragma unroll
        for (int v = 0; v < VSRC; ++v) {
            // h = |Y|^2 - 2<X,Y>  for two targets at once (v_pk_fma_f32 x3)
            f2 h = __builtin_elementwise_fma(xn[v], x01,
                   __builtin_elementwise_fma(yn[v], y01,
                   __builtin_elementwise_fma(zn[v], z01, w01)));
            acc[v] = fminf(acc[v], fminf(h.x, h.y));   // v_min3_f32
        }
    }

#pragma unroll
    for (int v = 0; v < VSRC; ++v) {
        float val = sw[v] + acc[v];       // d2_min over this chunk (>= 0)
        atomicMin(&out[b * NN + nbase + v * TPB + tid], __float_as_uint(val));
    }
}

__global__ __launch_bounds__(1024) void finalize_kernel(const uint4* __restrict__ minb4,
                                                        float* __restrict__ out) {
    float s0 = 0.f, s1 = 0.f;
    for (int i = threadIdx.x; i < 8192; i += 1024) {     // 8192 uint4 per direction
        uint4 u = minb4[i];
        s0 += __uint_as_float(u.x) + __uint_as_float(u.y) +
              __uint_as_float(u.z) + __uint_as_float(u.w);
        uint4 v = minb4[8192 + i];
        s1 += __uint_as_float(v.x) + __uint_as_float(v.y) +
              __uint_as_float(v.z) + __uint_as_float(v.w);
    }
#pragma unroll
    for (int o = 32; o; o >>= 1) {
        s0 += __shfl_down(s0, o);
        s1 += __shfl_down(s1, o);
    }
    __shared__ float r0[16], r1[16];
    int wave = threadIdx.x >> 6;
    if ((threadIdx.x & 63) == 0) { r0[wave] = s0; r1[wave] = s1; }
    __syncthreads();
    if (threadIdx.x == 0) {
        float a = 0.f, c = 0.f;
#pragma unroll
        for (int w = 0; w < 16; ++w) { a += r0[w]; c += r1[w]; }
        out[0] = 0.01f * (a / (float)(BB * NN) + c / (float)(BB * MM));
    }
}

extern "C" void kernel_launch(void* const* d_in, const int* in_sizes, int n_in,
                              void* d_out, int out_size, void* d_ws, size_t ws_size,
                              hipStream_t stream) {
    const float* s = (const float*)d_in[0];
    const float* t = (const float*)d_in[1];

    float4* s4 = (float4*)d_ws;
    float4* t4 = s4 + BB * NN;
    float4* sA = t4 + BB * MM;
    float4* sB = sA + BB * NN / 2;
    float4* tA = sB + BB * NN / 2;
    float4* tB = tA + BB * MM / 2;
    unsigned int* minb = (unsigned int*)(tB + BB * MM / 2);

    prep_kernel<<<(BB * NN / 2 + 255) / 256, 256, 0, stream>>>(
        s, t, s4, t4, sA, sB, tA, tB, (uint4*)minb);
    minpass_kernel<<<2 * BB * (NN / (TPB * VSRC)) * CS, TPB, 0, stream>>>(
        s4, t4, sA, sB, tA, tB, minb);
    finalize_kernel<<<1, 1024, 0, stream>>>((const uint4*)minb, (float*)d_out);
}

// Round 3
// 55.456 us; speedup vs baseline: 2.1462x; 1.0291x over previous
//
#include <hip/hip_runtime.h>

#define BB 4
#define NN 8192
#define MM 8192
#define TPB 256
#define VSRC 8             // source points per thread (registers)
#define CS 32              // M split into 32 chunks, one block each (atomicMin combine)
#define CHUNK 256          // targets per chunk
#define PAIRS (CHUNK / 2)  // 128 target-pairs staged in LDS (4 KB)
#define INF_BITS 0x7f7f7f7fu

typedef float f2 __attribute__((ext_vector_type(2)));

// ws layout (float4 units):
//   s4 [32768]  : source points as {x,y,z,|p|^2}
//   t4 [32768]  : target points likewise
//   sA [16384]  : source pair-transposed {x0,x1,y0,y1}
//   sB [16384]  : source pair-transposed {z0,z1,w0,w1}
//   tA [16384], tB [16384] : same for target
//   minb [65536 u32] : per-point running min bits (dir0 then dir1)

__global__ __launch_bounds__(256) void prep_kernel(
        const float* __restrict__ s, const float* __restrict__ t,
        float4* __restrict__ s4, float4* __restrict__ t4,
        float4* __restrict__ sA, float4* __restrict__ sB,
        float4* __restrict__ tA, float4* __restrict__ tB,
        uint4* __restrict__ minb4) {
    int i = blockIdx.x * blockDim.x + threadIdx.x;   // pair index, 16384 total
    if (i >= BB * NN / 2) return;
    {
        float a0 = s[6*i+0], b0 = s[6*i+1], c0 = s[6*i+2];
        float a1 = s[6*i+3], b1 = s[6*i+4], c1 = s[6*i+5];
        float w0 = a0*a0 + b0*b0 + c0*c0;
        float w1 = a1*a1 + b1*b1 + c1*c1;
        s4[2*i+0] = make_float4(a0, b0, c0, w0);
        s4[2*i+1] = make_float4(a1, b1, c1, w1);
        sA[i] = make_float4(a0, a1, b0, b1);
        sB[i] = make_float4(c0, c1, w0, w1);
    }
    {
        float a0 = t[6*i+0], b0 = t[6*i+1], c0 = t[6*i+2];
        float a1 = t[6*i+3], b1 = t[6*i+4], c1 = t[6*i+5];
        float w0 = a0*a0 + b0*b0 + c0*c0;
        float w1 = a1*a1 + b1*b1 + c1*c1;
        t4[2*i+0] = make_float4(a0, b0, c0, w0);
        t4[2*i+1] = make_float4(a1, b1, c1, w1);
        tA[i] = make_float4(a0, a1, b0, b1);
        tB[i] = make_float4(c0, c1, w0, w1);
    }
    minb4[i] = make_uint4(INF_BITS, INF_BITS, INF_BITS, INF_BITS);  // 16384*4 = 65536
}

__global__ __launch_bounds__(TPB) void minpass_kernel(
        const float4* __restrict__ s4, const float4* __restrict__ t4,
        const float4* __restrict__ sA, const float4* __restrict__ sB,
        const float4* __restrict__ tA, const float4* __restrict__ tB,
        unsigned int* __restrict__ minb) {
    __shared__ float4 TA[PAIRS];
    __shared__ float4 TB[PAIRS];

    int bid = blockIdx.x;
    int dir = bid >> 9;           // 512 blocks per direction
    bid &= 511;
    int c  = bid & (CS - 1);      // chunk of M   (0..31)
    int tt = (bid >> 5) & 3;      // src tile     (NT = NN/(TPB*VSRC) = 4)
    int b  = bid >> 7;            // batch        (0..3)

    const float4* __restrict__ S  = dir ? t4 : s4;   // source point layout
    const float4* __restrict__ PA = dir ? sA : tA;   // target pair layout
    const float4* __restrict__ PB = dir ? sB : tB;
    unsigned int* __restrict__ out = minb + dir * (BB * NN);

    int tid = threadIdx.x;

    // stage target chunk (pair-transposed) into LDS: half the threads each array
    int tbase = b * (MM / 2) + c * PAIRS;
    if (tid < PAIRS) TA[tid] = PA[tbase + tid];
    else             TB[tid - PAIRS] = PB[tbase + (tid - PAIRS)];

    // load this thread's source points; fold the -2 into the coords
    int nbase = tt * (TPB * VSRC);
    f2 xn[VSRC], yn[VSRC], zn[VSRC];
    float sw[VSRC], acc[VSRC];
#pragma unroll
    for (int v = 0; v < VSRC; ++v) {
        float4 sp = S[b * NN + nbase + v * TPB + tid];
        float x = -2.0f * sp.x, y = -2.0f * sp.y, z = -2.0f * sp.z;
        xn[v] = (f2){x, x};
        yn[v] = (f2){y, y};
        zn[v] = (f2){z, z};
        sw[v] = sp.w;
        acc[v] = 3.0e38f;
    }
    __syncthreads();

    // software-pipelined j-loop: load j+1 while computing j
    float4 aC = TA[0], bC = TB[0];
#pragma unroll 2
    for (int j = 0; j < PAIRS - 1; ++j) {
        float4 aN = TA[j + 1];
        float4 bN = TB[j + 1];
        f2 x01 = (f2){aC.x, aC.y};
        f2 y01 = (f2){aC.z, aC.w};
        f2 z01 = (f2){bC.x, bC.y};
        f2 w01 = (f2){bC.z, bC.w};
#pragma unroll
        for (int v = 0; v < VSRC; ++v) {
            f2 h = __builtin_elementwise_fma(xn[v], x01,
                   __builtin_elementwise_fma(yn[v], y01,
                   __builtin_elementwise_fma(zn[v], z01, w01)));
            acc[v] = fminf(acc[v], fminf(h.x, h.y));   // v_min3_f32
        }
        aC = aN; bC = bN;
    }
    {   // epilogue: last pair-column
        f2 x01 = (f2){aC.x, aC.y};
        f2 y01 = (f2){aC.z, aC.w};
        f2 z01 = (f2){bC.x, bC.y};
        f2 w01 = (f2){bC.z, bC.w};
#pragma unroll
        for (int v = 0; v < VSRC; ++v) {
            f2 h = __builtin_elementwise_fma(xn[v], x01,
                   __builtin_elementwise_fma(yn[v], y01,
                   __builtin_elementwise_fma(zn[v], z01, w01)));
            acc[v] = fminf(acc[v], fminf(h.x, h.y));
        }
    }

#pragma unroll
    for (int v = 0; v < VSRC; ++v) {
        float val = sw[v] + acc[v];       // d2_min over this chunk (>= 0)
        atomicMin(&out[b * NN + nbase + v * TPB + tid], __float_as_uint(val));
    }
}

__global__ __launch_bounds__(1024) void finalize_kernel(const uint4* __restrict__ minb4,
                                                        float* __restrict__ out) {
    float s0 = 0.f, s1 = 0.f;
    for (int i = threadIdx.x; i < 8192; i += 1024) {     // 8192 uint4 per direction
        uint4 u = minb4[i];
        s0 += __uint_as_float(u.x) + __uint_as_float(u.y) +
              __uint_as_float(u.z) + __uint_as_float(u.w);
        uint4 v = minb4[8192 + i];
        s1 += __uint_as_float(v.x) + __uint_as_float(v.y) +
              __uint_as_float(v.z) + __uint_as_float(v.w);
    }
#pragma unroll
    for (int o = 32; o; o >>= 1) {
        s0 += __shfl_down(s0, o);
        s1 += __shfl_down(s1, o);
    }
    __shared__ float r0[16], r1[16];
    int wave = threadIdx.x >> 6;
    if ((threadIdx.x & 63) == 0) { r0[wave] = s0; r1[wave] = s1; }
    __syncthreads();
    if (threadIdx.x == 0) {
        float a = 0.f, c = 0.f;
#pragma unroll
        for (int w = 0; w < 16; ++w) { a += r0[w]; c += r1[w]; }
        out[0] = 0.01f * (a / (float)(BB * NN) + c / (float)(BB * MM));
    }
}

extern "C" void kernel_launch(void* const* d_in, const int* in_sizes, int n_in,
                              void* d_out, int out_size, void* d_ws, size_t ws_size,
                              hipStream_t stream) {
    const float* s = (const float*)d_in[0];
    const float* t = (const float*)d_in[1];

    float4* s4 = (float4*)d_ws;
    float4* t4 = s4 + BB * NN;
    float4* sA = t4 + BB * MM;
    float4* sB = sA + BB * NN / 2;
    float4* tA = sB + BB * NN / 2;
    float4* tB = tA + BB * MM / 2;
    unsigned int* minb = (unsigned int*)(tB + BB * MM / 2);

    prep_kernel<<<(BB * NN / 2 + 255) / 256, 256, 0, stream>>>(
        s, t, s4, t4, sA, sB, tA, tB, (uint4*)minb);
    minpass_kernel<<<2 * BB * (NN / (TPB * VSRC)) * CS, TPB, 0, stream>>>(
        s4, t4, sA, sB, tA, tB, minb);
    finalize_kernel<<<1, 1024, 0, stream>>>((const uint4*)minb, (float*)d_out);
}

// Round 4
// 52.857 us; speedup vs baseline: 2.2518x; 1.0492x over previous
//
#include <hip/hip_runtime.h>

#define BB 4
#define NN 8192
#define MM 8192
#define TPB 256
#define VSRC 8             // source points per thread (registers)
#define CS 64              // M split into 64 chunks, one block each (atomicMin combine)
#define CHUNK 128          // targets per chunk
#define PAIRS (CHUNK / 2)  // 64 target-pairs per chunk, streamed via scalar loads
#define INF_BITS 0x7f7f7f7fu

typedef float f2 __attribute__((ext_vector_type(2)));

// ws layout (float4 units):
//   s4 [32768] : source points as {x,y,z,|p|^2}
//   t4 [32768] : target points likewise
//   sP [32768] : source pair stream, per pair i: [2i]={x0,x1,y0,y1} [2i+1]={z0,z1,w0,w1}
//   tP [32768] : same for target
//   minb [65536 u32] : per-point running min bits (dir0 then dir1)

__global__ __launch_bounds__(256) void prep_kernel(
        const float* __restrict__ s, const float* __restrict__ t,
        float4* __restrict__ s4, float4* __restrict__ t4,
        float4* __restrict__ sP, float4* __restrict__ tP,
        uint4* __restrict__ minb4) {
    int i = blockIdx.x * blockDim.x + threadIdx.x;   // pair index, 16384 total
    if (i >= BB * NN / 2) return;
    {
        float a0 = s[6*i+0], b0 = s[6*i+1], c0 = s[6*i+2];
        float a1 = s[6*i+3], b1 = s[6*i+4], c1 = s[6*i+5];
        float w0 = a0*a0 + b0*b0 + c0*c0;
        float w1 = a1*a1 + b1*b1 + c1*c1;
        s4[2*i+0] = make_float4(a0, b0, c0, w0);
        s4[2*i+1] = make_float4(a1, b1, c1, w1);
        sP[2*i+0] = make_float4(a0, a1, b0, b1);
        sP[2*i+1] = make_float4(c0, c1, w0, w1);
    }
    {
        float a0 = t[6*i+0], b0 = t[6*i+1], c0 = t[6*i+2];
        float a1 = t[6*i+3], b1 = t[6*i+4], c1 = t[6*i+5];
        float w0 = a0*a0 + b0*b0 + c0*c0;
        float w1 = a1*a1 + b1*b1 + c1*c1;
        t4[2*i+0] = make_float4(a0, b0, c0, w0);
        t4[2*i+1] = make_float4(a1, b1, c1, w1);
        tP[2*i+0] = make_float4(a0, a1, b0, b1);
        tP[2*i+1] = make_float4(c0, c1, w0, w1);
    }
    minb4[i] = make_uint4(INF_BITS, INF_BITS, INF_BITS, INF_BITS);  // 16384*4 = 65536
}

__global__ __launch_bounds__(TPB, 4) void minpass_kernel(
        const float4* __restrict__ s4, const float4* __restrict__ t4,
        const float4* __restrict__ sP, const float4* __restrict__ tP,
        unsigned int* __restrict__ minb) {
    int bid = blockIdx.x;
    int dir = bid >> 10;          // 1024 blocks per direction
    bid &= 1023;
    int c  = bid & (CS - 1);      // chunk of M   (0..63)
    int tt = (bid >> 6) & 3;      // src tile     (NT = NN/(TPB*VSRC) = 4)
    int b  = bid >> 8;            // batch        (0..3)

    const float4* __restrict__ S = dir ? t4 : s4;   // per-thread source points
    const float4* __restrict__ P = (dir ? sP : tP)  // wave-uniform target stream -> s_load
                                   + (size_t)(b * (MM / 2) + c * PAIRS) * 2;
    unsigned int* __restrict__ out = minb + dir * (BB * NN);

    int tid = threadIdx.x;

    // load this thread's source points; fold the -2 into the coords
    int nbase = tt * (TPB * VSRC);
    f2 xn[VSRC], yn[VSRC], zn[VSRC];
    float sw[VSRC], acc[VSRC];
#pragma unroll
    for (int v = 0; v < VSRC; ++v) {
        float4 sp = S[b * NN + nbase + v * TPB + tid];
        float x = -2.0f * sp.x, y = -2.0f * sp.y, z = -2.0f * sp.z;
        xn[v] = (f2){x, x};
        yn[v] = (f2){y, y};
        zn[v] = (f2){z, z};
        sw[v] = sp.w;
        acc[v] = 3.0e38f;
    }

    // j-loop: target pair-columns come in via wave-uniform scalar loads (SGPRs),
    // so the vector-memory and LDS pipes are completely idle here.
#pragma unroll 4
    for (int j = 0; j < PAIRS; ++j) {
        float4 A = P[2*j];                // {x0,x1,y0,y1}  (s_load_dwordx4)
        float4 B = P[2*j+1];              // {z0,z1,w0,w1}
        f2 x01 = (f2){A.x, A.y};
        f2 y01 = (f2){A.z, A.w};
        f2 z01 = (f2){B.x, B.y};
        f2 w01 = (f2){B.z, B.w};
#pragma unroll
        for (int v = 0; v < VSRC; ++v) {
            // h = |Y|^2 - 2<X,Y> for two targets at once (3x v_pk_fma_f32)
            f2 h = __builtin_elementwise_fma(xn[v], x01,
                   __builtin_elementwise_fma(yn[v], y01,
                   __builtin_elementwise_fma(zn[v], z01, w01)));
            acc[v] = fminf(acc[v], fminf(h.x, h.y));   // v_min3_f32
        }
    }

#pragma unroll
    for (int v = 0; v < VSRC; ++v) {
        float val = sw[v] + acc[v];       // d2_min over this chunk (>= 0)
        atomicMin(&out[b * NN + nbase + v * TPB + tid], __float_as_uint(val));
    }
}

__global__ __launch_bounds__(1024) void finalize_kernel(const uint4* __restrict__ minb4,
                                                        float* __restrict__ out) {
    float s0 = 0.f, s1 = 0.f;
    for (int i = threadIdx.x; i < 8192; i += 1024) {     // 8192 uint4 per direction
        uint4 u = minb4[i];
        s0 += __uint_as_float(u.x) + __uint_as_float(u.y) +
              __uint_as_float(u.z) + __uint_as_float(u.w);
        uint4 v = minb4[8192 + i];
        s1 += __uint_as_float(v.x) + __uint_as_float(v.y) +
              __uint_as_float(v.z) + __uint_as_float(v.w);
    }
#pragma unroll
    for (int o = 32; o; o >>= 1) {
        s0 += __shfl_down(s0, o);
        s1 += __shfl_down(s1, o);
    }
    __shared__ float r0[16], r1[16];
    int wave = threadIdx.x >> 6;
    if ((threadIdx.x & 63) == 0) { r0[wave] = s0; r1[wave] = s1; }
    __syncthreads();
    if (threadIdx.x == 0) {
        float a = 0.f, c = 0.f;
#pragma unroll
        for (int w = 0; w < 16; ++w) { a += r0[w]; c += r1[w]; }
        out[0] = 0.01f * (a / (float)(BB * NN) + c / (float)(BB * MM));
    }
}

extern "C" void kernel_launch(void* const* d_in, const int* in_sizes, int n_in,
                              void* d_out, int out_size, void* d_ws, size_t ws_size,
                              hipStream_t stream) {
    const float* s = (const float*)d_in[0];
    const float* t = (const float*)d_in[1];

    float4* s4 = (float4*)d_ws;
    float4* t4 = s4 + BB * NN;
    float4* sP = t4 + BB * MM;
    float4* tP = sP + BB * NN;
    unsigned int* minb = (unsigned int*)(tP + BB * MM);

    prep_kernel<<<(BB * NN / 2 + 255) / 256, 256, 0, stream>>>(
        s, t, s4, t4, sP, tP, (uint4*)minb);
    minpass_kernel<<<2 * BB * (NN / (TPB * VSRC)) * CS, TPB, 0, stream>>>(
        s4, t4, sP, tP, minb);
    finalize_kernel<<<1, 1024, 0, stream>>>((const uint4*)minb, (float*)d_out);
}

// Round 6
// 40.217 us; speedup vs baseline: 2.9595x; 1.3143x over previous
//
#include <hip/hip_runtime.h>

#define BB 4
#define NN 8192            // points per batch per side
#define INF_BITS 0x7f7f7f7fu

typedef __attribute__((ext_vector_type(8)))  short bf16x8;   // 8 bf16 = 4 VGPRs
typedef __attribute__((ext_vector_type(16))) float f32x16;   // MFMA 32x32 acc

// ws layout:
//   sApk [65536 bf16x8] : source A-operand fragments (-2 folded + norm slots)  1 MB
//   sBpk [65536 bf16x8] : source B-operand fragments (plain coords + 1.0)      1 MB
//   tApk, tBpk          : same for target                                      2 MB
//   snorm[32768] f32, tnorm[32768] f32
//   minb [65536 u32]    : per-point running min bits (dir0: per-source, dir1: per-target)
//
// v_mfma_f32_32x32x16_bf16 operand maps used:
//   A: row = lane&31, k = 8*(lane>>5)+e     B: col = lane&31, k = 8*(lane>>5)+e
//   C/D: col = lane&31, row = (reg&3)+8*(reg>>2)+4*(lane>>5)   [verified, learn_hip m101]
// K slots (A-side x B-side), computing h = |A-point|^2 - 2<A-point, B-point>:
//   k0..k2: (-2xh)(x'h), (-2xl)(x'h), (-2xh)(x'l)   k3..k5: same for y
//   k6..k8: same for z                               k9,k10: (nh)(1), (nl)(1)   k11..15: 0

__device__ __forceinline__ unsigned short bf_hi(float f) {
    unsigned u = __float_as_uint(f);
    u += 0x7fffu + ((u >> 16) & 1u);           // RTNE, finite inputs
    return (unsigned short)(u >> 16);
}

__global__ __launch_bounds__(256) void prep_kernel(
        const float* __restrict__ s, const float* __restrict__ t,
        bf16x8* __restrict__ sApk, bf16x8* __restrict__ sBpk,
        bf16x8* __restrict__ tApk, bf16x8* __restrict__ tBpk,
        float* __restrict__ snorm, float* __restrict__ tnorm,
        unsigned* __restrict__ minb) {
    int i = blockIdx.x * 256 + threadIdx.x;    // 0..65535
    int set = i >> 15;                          // 0 = source, 1 = target
    int p = i & 32767;                          // global point index (b*8192 + idx)
    const float* in = set ? t : s;
    float x = in[3*p], y = in[3*p+1], z = in[3*p+2];

    unsigned short xh = bf_hi(x); float fxh = __uint_as_float((unsigned)xh << 16);
    unsigned short yh = bf_hi(y); float fyh = __uint_as_float((unsigned)yh << 16);
    unsigned short zh = bf_hi(z); float fzh = __uint_as_float((unsigned)zh << 16);
    unsigned short xl = bf_hi(x - fxh);
    unsigned short yl = bf_hi(y - fyh);
    unsigned short zl = bf_hi(z - fzh);
    float fxl = __uint_as_float((unsigned)xl << 16);
    float fyl = __uint_as_float((unsigned)yl << 16);
    float fzl = __uint_as_float((unsigned)zl << 16);
    // -2 * (exact bf16 value) is exact in bf16
    unsigned short mxh = bf_hi(-2.0f*fxh), mxl = bf_hi(-2.0f*fxl);
    unsigned short myh = bf_hi(-2.0f*fyh), myl = bf_hi(-2.0f*fyl);
    unsigned short mzh = bf_hi(-2.0f*fzh), mzl = bf_hi(-2.0f*fzl);

    float n = x*x + y*y + z*z;
    unsigned short nh = bf_hi(n); float fnh = __uint_as_float((unsigned)nh << 16);
    unsigned short nl = bf_hi(n - fnh);
    const short one = (short)0x3F80;            // bf16 1.0

    bf16x8 alo = {(short)mxh,(short)mxl,(short)mxh,(short)myh,(short)myl,(short)myh,(short)mzh,(short)mzl};
    bf16x8 ahi = {(short)mzh,(short)nh,(short)nl,0,0,0,0,0};
    bf16x8 blo = {(short)xh,(short)xh,(short)xl,(short)yh,(short)yh,(short)yl,(short)zh,(short)zh};
    bf16x8 bhi = {(short)zl,one,one,0,0,0,0,0};

    bf16x8* A = set ? tApk : sApk;
    bf16x8* B = set ? tBpk : sBpk;
    int tile = p >> 5, l = p & 31;
    A[tile*64 + l]      = alo;
    A[tile*64 + 32 + l] = ahi;
    B[tile*64 + l]      = blo;
    B[tile*64 + 32 + l] = bhi;

    (set ? tnorm : snorm)[p] = n;
    minb[i] = INF_BITS;
}

__device__ __forceinline__ void tile_step(const bf16x8& A0, const bf16x8& A1,
                                          const bf16x8* Bf, f32x16* run, const f32x16& cz) {
#pragma unroll
    for (int t = 0; t < 4; ++t) {
        f32x16 aA = __builtin_amdgcn_mfma_f32_32x32x16_bf16(A0, Bf[t], cz, 0, 0, 0);
        f32x16 aB = __builtin_amdgcn_mfma_f32_32x32x16_bf16(A1, Bf[t], cz, 0, 0, 0);
#pragma unroll
        for (int i = 0; i < 16; ++i)
            run[t][i] = fminf(fminf(aA[i], aB[i]), run[t][i]);   // v_min3_f32
    }
}

// one wave per block; block = (dir, batch, source-group of 128, target-chunk of 1024)
__global__ __launch_bounds__(64) void minpass_kernel(
        const bf16x8* __restrict__ sApk, const bf16x8* __restrict__ sBpk,
        const bf16x8* __restrict__ tApk, const bf16x8* __restrict__ tBpk,
        const float* __restrict__ snorm, const float* __restrict__ tnorm,
        unsigned* __restrict__ minb) {
    int bid = blockIdx.x;
    int tc  = bid & 7;
    int sg  = (bid >> 3) & 63;
    int b   = (bid >> 9) & 3;
    int dir = bid >> 11;

    // dir0: min per SOURCE over targets -> A = targets (rows), B = sources (cols)
    const bf16x8* Ap = dir ? sApk : tApk;
    const bf16x8* Bp = dir ? tBpk : sBpk;
    const float*  nrm = dir ? tnorm : snorm;    // norm of the B-side (per-column) point
    unsigned* out = minb + dir * (BB * NN) + b * NN;

    int lane = threadIdx.x;

    bf16x8 Bf[4];
#pragma unroll
    for (int t = 0; t < 4; ++t)
        Bf[t] = Bp[(b * 256 + sg * 4 + t) * 64 + lane];

    f32x16 run[4];
#pragma unroll
    for (int t = 0; t < 4; ++t)
#pragma unroll
        for (int i = 0; i < 16; ++i) run[t][i] = 3.0e38f;

    f32x16 cz = {};   // persistent zero C operand

    const bf16x8* Abase = Ap + (b * 256 + tc * 32) * 64 + lane;
    bf16x8 A0 = Abase[0];
    bf16x8 A1 = Abase[64];
#pragma unroll 1
    for (int j = 0; j < 30; j += 2) {
        bf16x8 N0 = Abase[(j + 2) * 64];    // prefetch next tile pair
        bf16x8 N1 = Abase[(j + 3) * 64];
        tile_step(A0, A1, Bf, run, cz);
        A0 = N0; A1 = N1;
    }
    tile_step(A0, A1, Bf, run, cz);         // tiles 30, 31

#pragma unroll
    for (int t = 0; t < 4; ++t) {
        f32x16 r = run[t];
        float a0 = fminf(r[0], r[8]),  a1 = fminf(r[1], r[9]);
        float a2 = fminf(r[2], r[10]), a3 = fminf(r[3], r[11]);
        float a4 = fminf(a0, fminf(r[4], r[12])), a5 = fminf(a1, fminf(r[5], r[13]));
        float a6 = fminf(a2, fminf(r[6], r[14])), a7 = fminf(a3, fminf(r[7], r[15]));
        float m  = fminf(fminf(a4, a5), fminf(a6, a7));
        m = fminf(m, __shfl_xor(m, 32));    // combine the two half-wave row sets
        int src = (sg * 4 + t) * 32 + (lane & 31);
        // m already holds |t|^2 - 2<s,t> (norm fed via k9/k10); add |s|^2, clamp >= 0
        float val = fmaxf(m + nrm[b * NN + src], 0.0f);
        if (lane < 32)
            atomicMin(out + src, __float_as_uint(val));
    }
}

__global__ __launch_bounds__(1024) void finalize_kernel(const uint4* __restrict__ minb4,
                                                        float* __restrict__ out) {
    float s0 = 0.f, s1 = 0.f;
    for (int i = threadIdx.x; i < 8192; i += 1024) {
        uint4 u = minb4[i];
        s0 += __uint_as_float(u.x) + __uint_as_float(u.y) +
              __uint_as_float(u.z) + __uint_as_float(u.w);
        uint4 v = minb4[8192 + i];
        s1 += __uint_as_float(v.x) + __uint_as_float(v.y) +
              __uint_as_float(v.z) + __uint_as_float(v.w);
    }
#pragma unroll
    for (int o = 32; o; o >>= 1) {
        s0 += __shfl_down(s0, o);
        s1 += __shfl_down(s1, o);
    }
    __shared__ float r0[16], r1[16];
    int wave = threadIdx.x >> 6;
    if ((threadIdx.x & 63) == 0) { r0[wave] = s0; r1[wave] = s1; }
    __syncthreads();
    if (threadIdx.x == 0) {
        float a = 0.f, c = 0.f;
#pragma unroll
        for (int w = 0; w < 16; ++w) { a += r0[w]; c += r1[w]; }
        out[0] = 0.01f * (a / (float)(BB * NN) + c / (float)(BB * NN));
    }
}

extern "C" void kernel_launch(void* const* d_in, const int* in_sizes, int n_in,
                              void* d_out, int out_size, void* d_ws, size_t ws_size,
                              hipStream_t stream) {
    const float* s = (const float*)d_in[0];
    const float* t = (const float*)d_in[1];

    bf16x8* sApk = (bf16x8*)d_ws;
    bf16x8* sBpk = sApk + 65536;
    bf16x8* tApk = sBpk + 65536;
    bf16x8* tBpk = tApk + 65536;
    float*  snorm = (float*)(tBpk + 65536);
    float*  tnorm = snorm + 32768;
    unsigned* minb = (unsigned*)(tnorm + 32768);

    prep_kernel<<<256, 256, 0, stream>>>(s, t, sApk, sBpk, tApk, tBpk, snorm, tnorm, minb);
    minpass_kernel<<<4096, 64, 0, stream>>>(sApk, sBpk, tApk, tBpk, snorm, tnorm, minb);
    finalize_kernel<<<1, 1024, 0, stream>>>((const uint4*)minb, (float*)d_out);
}

// Round 7
// 39.733 us; speedup vs baseline: 2.9956x; 1.0122x over previous
//
#include <hip/hip_runtime.h>

#define BB 4
#define NN 8192            // points per batch per side
#define INF_BITS 0x7f7f7f7fu

typedef __attribute__((ext_vector_type(8)))  short bf16x8;   // 8 bf16 = 4 VGPRs
typedef __attribute__((ext_vector_type(16))) float f32x16;   // MFMA 32x32 acc

// ws layout:
//   sApk [65536 bf16x8] : source A-operand fragments (-2 folded + norm slots)  1 MB
//   sBpk [65536 bf16x8] : source B-operand fragments (plain coords + 1.0)      1 MB
//   tApk, tBpk          : same for target                                      2 MB
//   snorm[32768] f32, tnorm[32768] f32
//   minb [65536 u32]    : per-point running min bits (dir0: per-source, dir1: per-target)
//
// v_mfma_f32_32x32x16_bf16 operand maps (verified by round-6 absmax=0):
//   A: row = lane&31, k = 8*(lane>>5)+e     B: col = lane&31, k = 8*(lane>>5)+e
//   C/D: col = lane&31, row = (reg&3)+8*(reg>>2)+4*(lane>>5)
// K slots: k0..k8 = hi/lo split cross terms, k9,k10 = A-side norm * 1.0, rest 0.

__device__ __forceinline__ unsigned short bf_hi(float f) {
    unsigned u = __float_as_uint(f);
    u += 0x7fffu + ((u >> 16) & 1u);           // RTNE, finite inputs
    return (unsigned short)(u >> 16);
}

__device__ __forceinline__ float min3f(float a, float b, float c) {
    float d;
    asm("v_min3_f32 %0, %1, %2, %3" : "=v"(d) : "v"(a), "v"(b), "v"(c));
    return d;
}

__global__ __launch_bounds__(256) void prep_kernel(
        const float* __restrict__ s, const float* __restrict__ t,
        bf16x8* __restrict__ sApk, bf16x8* __restrict__ sBpk,
        bf16x8* __restrict__ tApk, bf16x8* __restrict__ tBpk,
        float* __restrict__ snorm, float* __restrict__ tnorm,
        unsigned* __restrict__ minb) {
    int i = blockIdx.x * 256 + threadIdx.x;    // 0..65535
    int set = i >> 15;                          // 0 = source, 1 = target
    int p = i & 32767;                          // global point index (b*8192 + idx)
    const float* in = set ? t : s;
    float x = in[3*p], y = in[3*p+1], z = in[3*p+2];

    unsigned short xh = bf_hi(x); float fxh = __uint_as_float((unsigned)xh << 16);
    unsigned short yh = bf_hi(y); float fyh = __uint_as_float((unsigned)yh << 16);
    unsigned short zh = bf_hi(z); float fzh = __uint_as_float((unsigned)zh << 16);
    unsigned short xl = bf_hi(x - fxh);
    unsigned short yl = bf_hi(y - fyh);
    unsigned short zl = bf_hi(z - fzh);
    float fxl = __uint_as_float((unsigned)xl << 16);
    float fyl = __uint_as_float((unsigned)yl << 16);
    float fzl = __uint_as_float((unsigned)zl << 16);
    // -2 * (exact bf16 value) is exact in bf16
    unsigned short mxh = bf_hi(-2.0f*fxh), mxl = bf_hi(-2.0f*fxl);
    unsigned short myh = bf_hi(-2.0f*fyh), myl = bf_hi(-2.0f*fyl);
    unsigned short mzh = bf_hi(-2.0f*fzh), mzl = bf_hi(-2.0f*fzl);

    float n = x*x + y*y + z*z;
    unsigned short nh = bf_hi(n); float fnh = __uint_as_float((unsigned)nh << 16);
    unsigned short nl = bf_hi(n - fnh);
    const short one = (short)0x3F80;            // bf16 1.0

    bf16x8 alo = {(short)mxh,(short)mxl,(short)mxh,(short)myh,(short)myl,(short)myh,(short)mzh,(short)mzl};
    bf16x8 ahi = {(short)mzh,(short)nh,(short)nl,0,0,0,0,0};
    bf16x8 blo = {(short)xh,(short)xh,(short)xl,(short)yh,(short)yh,(short)yl,(short)zh,(short)zh};
    bf16x8 bhi = {(short)zl,one,one,0,0,0,0,0};

    bf16x8* A = set ? tApk : sApk;
    bf16x8* B = set ? tBpk : sBpk;
    int tile = p >> 5, l = p & 31;
    A[tile*64 + l]      = alo;
    A[tile*64 + 32 + l] = ahi;
    B[tile*64 + l]      = blo;
    B[tile*64 + 32 + l] = bhi;

    (set ? tnorm : snorm)[p] = n;
    minb[i] = INF_BITS;
}

// one wave per block; block = (dir, batch, source-group of 64, target-chunk of 1024)
__global__ __launch_bounds__(64) void minpass_kernel(
        const bf16x8* __restrict__ sApk, const bf16x8* __restrict__ sBpk,
        const bf16x8* __restrict__ tApk, const bf16x8* __restrict__ tBpk,
        const float* __restrict__ snorm, const float* __restrict__ tnorm,
        unsigned* __restrict__ minb) {
    int bid = blockIdx.x;
    int tc  = bid & 7;            // A-chunk: 32 tiles of 32 rows = 1024 targets
    int sg  = (bid >> 3) & 127;   // source-group: 2 B-tiles = 64 sources
    int b   = (bid >> 10) & 3;
    int dir = bid >> 12;

    // dir0: min per SOURCE over targets -> A = targets (rows), B = sources (cols)
    const bf16x8* Ap = dir ? sApk : tApk;
    const bf16x8* Bp = dir ? tBpk : sBpk;
    const float*  nrm = dir ? tnorm : snorm;    // norm of the B-side (per-column) point
    unsigned* out = minb + dir * (BB * NN) + b * NN;

    int lane = threadIdx.x;

    bf16x8 Bf0 = Bp[(b * 256 + sg * 2 + 0) * 64 + lane];
    bf16x8 Bf1 = Bp[(b * 256 + sg * 2 + 1) * 64 + lane];

    f32x16 run0, run1;
#pragma unroll
    for (int i = 0; i < 16; ++i) { run0[i] = 3.0e38f; run1[i] = 3.0e38f; }

    f32x16 cz = {};   // persistent zero C operand

    const bf16x8* Ab = Ap + (b * 256 + tc * 32) * 64 + lane;

    // 2-pair-deep software pipeline over 16 A-tile pairs
    bf16x8 C0 = Ab[0],   C1 = Ab[64];
    bf16x8 P0 = Ab[128], P1 = Ab[192];
#pragma unroll 1
    for (int jp = 0; jp < 14; ++jp) {
        bf16x8 N0 = Ab[(2 * jp + 4) * 64];
        bf16x8 N1 = Ab[(2 * jp + 5) * 64];
        f32x16 q0 = __builtin_amdgcn_mfma_f32_32x32x16_bf16(C0, Bf0, cz, 0, 0, 0);
        f32x16 q1 = __builtin_amdgcn_mfma_f32_32x32x16_bf16(C1, Bf0, cz, 0, 0, 0);
#pragma unroll
        for (int i = 0; i < 16; ++i) run0[i] = min3f(q0[i], q1[i], run0[i]);
        f32x16 r0 = __builtin_amdgcn_mfma_f32_32x32x16_bf16(C0, Bf1, cz, 0, 0, 0);
        f32x16 r1 = __builtin_amdgcn_mfma_f32_32x32x16_bf16(C1, Bf1, cz, 0, 0, 0);
#pragma unroll
        for (int i = 0; i < 16; ++i) run1[i] = min3f(r0[i], r1[i], run1[i]);
        C0 = P0; C1 = P1; P0 = N0; P1 = N1;
    }
#pragma unroll
    for (int e = 0; e < 2; ++e) {    // epilogue: pairs 14, 15
        f32x16 q0 = __builtin_amdgcn_mfma_f32_32x32x16_bf16(C0, Bf0, cz, 0, 0, 0);
        f32x16 q1 = __builtin_amdgcn_mfma_f32_32x32x16_bf16(C1, Bf0, cz, 0, 0, 0);
#pragma unroll
        for (int i = 0; i < 16; ++i) run0[i] = min3f(q0[i], q1[i], run0[i]);
        f32x16 r0 = __builtin_amdgcn_mfma_f32_32x32x16_bf16(C0, Bf1, cz, 0, 0, 0);
        f32x16 r1 = __builtin_amdgcn_mfma_f32_32x32x16_bf16(C1, Bf1, cz, 0, 0, 0);
#pragma unroll
        for (int i = 0; i < 16; ++i) run1[i] = min3f(r0[i], r1[i], run1[i]);
        C0 = P0; C1 = P1;
    }

#pragma unroll
    for (int t = 0; t < 2; ++t) {
        const f32x16& r = t ? run1 : run0;
        float g0 = min3f(r[0],  r[1],  r[2]);
        float g1 = min3f(r[3],  r[4],  r[5]);
        float g2 = min3f(r[6],  r[7],  r[8]);
        float g3 = min3f(r[9],  r[10], r[11]);
        float g4 = min3f(r[12], r[13], r[14]);
        float h0 = min3f(g0, g1, g2);
        float h1 = min3f(g3, g4, r[15]);
        float m  = fminf(h0, h1);
        m = fminf(m, __shfl_xor(m, 32));    // combine the two half-wave row sets
        int src = sg * 64 + t * 32 + (lane & 31);
        // m holds |t|^2 - 2<s,t> (norm fed via k9/k10); add |s|^2, clamp >= 0
        float val = fmaxf(m + nrm[b * NN + src], 0.0f);
        if (lane < 32)
            atomicMin(out + src, __float_as_uint(val));
    }
}

__global__ __launch_bounds__(1024) void finalize_kernel(const uint4* __restrict__ minb4,
                                                        float* __restrict__ out) {
    float s0 = 0.f, s1 = 0.f;
    for (int i = threadIdx.x; i < 8192; i += 1024) {
        uint4 u = minb4[i];
        s0 += __uint_as_float(u.x) + __uint_as_float(u.y) +
              __uint_as_float(u.z) + __uint_as_float(u.w);
        uint4 v = minb4[8192 + i];
        s1 += __uint_as_float(v.x) + __uint_as_float(v.y) +
              __uint_as_float(v.z) + __uint_as_float(v.w);
    }
#pragma unroll
    for (int o = 32; o; o >>= 1) {
        s0 += __shfl_down(s0, o);
        s1 += __shfl_down(s1, o);
    }
    __shared__ float r0[16], r1[16];
    int wave = threadIdx.x >> 6;
    if ((threadIdx.x & 63) == 0) { r0[wave] = s0; r1[wave] = s1; }
    __syncthreads();
    if (threadIdx.x == 0) {
        float a = 0.f, c = 0.f;
#pragma unroll
        for (int w = 0; w < 16; ++w) { a += r0[w]; c += r1[w]; }
        out[0] = 0.01f * (a / (float)(BB * NN) + c / (float)(BB * NN));
    }
}

extern "C" void kernel_launch(void* const* d_in, const int* in_sizes, int n_in,
                              void* d_out, int out_size, void* d_ws, size_t ws_size,
                              hipStream_t stream) {
    const float* s = (const float*)d_in[0];
    const float* t = (const float*)d_in[1];

    bf16x8* sApk = (bf16x8*)d_ws;
    bf16x8* sBpk = sApk + 65536;
    bf16x8* tApk = sBpk + 65536;
    bf16x8* tBpk = tApk + 65536;
    float*  snorm = (float*)(tBpk + 65536);
    float*  tnorm = snorm + 32768;
    unsigned* minb = (unsigned*)(tnorm + 32768);

    prep_kernel<<<256, 256, 0, stream>>>(s, t, sApk, sBpk, tApk, tBpk, snorm, tnorm, minb);
    minpass_kernel<<<2 * 4 * 128 * 8, 64, 0, stream>>>(sApk, sBpk, tApk, tBpk, snorm, tnorm, minb);
    finalize_kernel<<<1, 1024, 0, stream>>>((const uint4*)minb, (float*)d_out);
}